// Round 3
// baseline (1093.355 us; speedup 1.0000x reference)
//
#include <hip/hip_runtime.h>
#include <hip/hip_bf16.h>
#include <math.h>

typedef __bf16 bf16x8 __attribute__((ext_vector_type(8)));
typedef float  f32x4  __attribute__((ext_vector_type(4)));
typedef float  f32x16 __attribute__((ext_vector_type(16)));

#define MFMA16(a, b, c) __builtin_amdgcn_mfma_f32_16x16x32_bf16((a), (b), (c), 0, 0, 0)
#define MFMA32(a, b, c) __builtin_amdgcn_mfma_f32_32x32x16_bf16((a), (b), (c), 0, 0, 0)

static constexpr int    kB  = 16;
static constexpr int    kS  = 2048;
static constexpr int    kC  = 512;
static constexpr size_t kNE = (size_t)kB * kS * kC;  // 16777216

static __device__ __forceinline__ void split_bf16(float v, __bf16 &hi, __bf16 &lo) {
  hi = (__bf16)v;
  lo = (__bf16)(v - (float)hi);
}

// async 16B global->LDS; HW dest = wave-uniform base + lane*16, our per-lane
// pointers are exactly that.
static __device__ __forceinline__ void gl2lds16(const __bf16* g, __bf16* l) {
  __builtin_amdgcn_global_load_lds(
      (const __attribute__((address_space(1))) void*)g,
      (__attribute__((address_space(3))) void*)l, 16, 0, 0);
}

static __device__ __forceinline__ void stage_split16(
    const float* __restrict__ src, __bf16* hi, __bf16* lo, int o) {
  float4 v0 = *(const float4*)(src + 0);
  float4 v1 = *(const float4*)(src + 4);
  float4 v2 = *(const float4*)(src + 8);
  float4 v3 = *(const float4*)(src + 12);
  float vv[16] = {v0.x, v0.y, v0.z, v0.w, v1.x, v1.y, v1.z, v1.w,
                  v2.x, v2.y, v2.z, v2.w, v3.x, v3.y, v3.z, v3.w};
  bf16x8 h0, h1, l0, l1;
#pragma unroll
  for (int i = 0; i < 8; ++i) {
    __bf16 a, b;
    split_bf16(vv[i], a, b);     h0[i] = a; l0[i] = b;
    split_bf16(vv[8 + i], a, b); h1[i] = a; l1[i] = b;
  }
  *(bf16x8*)&hi[o]     = h0;
  *(bf16x8*)&hi[o + 8] = h1;
  *(bf16x8*)&lo[o]     = l0;
  *(bf16x8*)&lo[o + 8] = l1;
}

// ---------------- K1a: t = tanh(x'), split to bf16 hi/lo ----------------
__global__ __launch_bounds__(256) void k_tanh_split(
    const float* __restrict__ xp, __bf16* __restrict__ th, __bf16* __restrict__ tl) {
  size_t i = ((size_t)blockIdx.x * 256 + threadIdx.x) * 8;
  float4 a = *(const float4*)(xp + i);
  float4 b = *(const float4*)(xp + i + 4);
  float v[8] = {a.x, a.y, a.z, a.w, b.x, b.y, b.z, b.w};
  bf16x8 h, l;
#pragma unroll
  for (int k = 0; k < 8; ++k) {
    float t = tanhf(v[k]);
    __bf16 hh, ll;
    split_bf16(t, hh, ll);
    h[k] = hh; l[k] = ll;
  }
  *(bf16x8*)(th + i) = h;
  *(bf16x8*)(tl + i) = l;
}

// ---------------- K1c: x (fp32 [b][t][c]) -> bf16 transposed [b][c][t] ----------------
__global__ __launch_bounds__(256) void k_transpose_x(
    const float* __restrict__ x, __bf16* __restrict__ xbt) {
  __shared__ float tile[64][65];
  int bid = blockIdx.x;              // 16 * 32 * 8 = 4096
  int b   = bid >> 8;
  int t0  = ((bid >> 3) & 31) * 64;
  int c0  = (bid & 7) * 64;
  int row = threadIdx.x >> 2;
  int seg = threadIdx.x & 3;
  const float* src = x + (size_t)(b * kS + t0 + row) * kC + c0 + seg * 16;
  float4 v0 = *(const float4*)(src + 0);
  float4 v1 = *(const float4*)(src + 4);
  float4 v2 = *(const float4*)(src + 8);
  float4 v3 = *(const float4*)(src + 12);
  float vv[16] = {v0.x, v0.y, v0.z, v0.w, v1.x, v1.y, v1.z, v1.w,
                  v2.x, v2.y, v2.z, v2.w, v3.x, v3.y, v3.z, v3.w};
#pragma unroll
  for (int i = 0; i < 16; ++i) tile[row][seg * 16 + i] = vv[i];
  __syncthreads();
  bf16x8 o0, o1;
#pragma unroll
  for (int i = 0; i < 8; ++i) o0[i] = (__bf16)tile[seg * 16 + i][row];
#pragma unroll
  for (int i = 0; i < 8; ++i) o1[i] = (__bf16)tile[seg * 16 + 8 + i][row];
  __bf16* dst = xbt + (size_t)(b * kC + c0 + row) * kS + t0 + seg * 16;
  *(bf16x8*)(dst)     = o0;
  *(bf16x8*)(dst + 8) = o1;
}

// ---------------- K1b: q = x' @ W^T + bias, split-bf16 3-MFMA ----------------
__global__ __launch_bounds__(256) void k_qgemm(
    const float* __restrict__ xp, const float* __restrict__ W,
    const float* __restrict__ bias, __bf16* __restrict__ qh, __bf16* __restrict__ ql) {
  __shared__ __align__(16) __bf16 lds[4 * 4608];
  __bf16* Ah = lds;
  __bf16* Al = lds + 4608;
  __bf16* Bh = lds + 9216;
  __bf16* Bl = lds + 13824;

  int bid = blockIdx.x;
  int n0  = (bid & 7) * 64;
  int m0  = (bid >> 3) * 64;

  int tid  = threadIdx.x;
  int lane = tid & 63;
  int wave = tid >> 6;
  int qd   = lane >> 4;
  int cl   = lane & 15;
  int row  = tid >> 2;
  int seg  = tid & 3;

  f32x4 acc[4] = {};

  for (int kc = 0; kc < 8; ++kc) {
    stage_split16(xp + (size_t)(m0 + row) * kC + kc * 64 + seg * 16, Ah, Al, row * 72 + seg * 16);
    stage_split16(W  + (size_t)(n0 + row) * kC + kc * 64 + seg * 16, Bh, Bl, row * 72 + seg * 16);
    __syncthreads();
#pragma unroll
    for (int ks = 0; ks < 2; ++ks) {
      int ka = ks * 32 + qd * 8;
      bf16x8 ah = *(const bf16x8*)&Ah[(wave * 16 + cl) * 72 + ka];
      bf16x8 al = *(const bf16x8*)&Al[(wave * 16 + cl) * 72 + ka];
#pragma unroll
      for (int j = 0; j < 4; ++j) {
        bf16x8 bh = *(const bf16x8*)&Bh[(j * 16 + cl) * 72 + ka];
        bf16x8 bl = *(const bf16x8*)&Bl[(j * 16 + cl) * 72 + ka];
        acc[j] = MFMA16(ah, bh, acc[j]);
        acc[j] = MFMA16(ah, bl, acc[j]);
        acc[j] = MFMA16(al, bh, acc[j]);
      }
    }
    __syncthreads();
  }
#pragma unroll
  for (int j = 0; j < 4; ++j) {
    int d = n0 + j * 16 + cl;
    float bv = bias[d];
#pragma unroll
    for (int r = 0; r < 4; ++r) {
      int m = m0 + wave * 16 + qd * 4 + r;
      float v = acc[j][r] + bv;
      __bf16 hh, ll;
      split_bf16(v, hh, ll);
      qh[(size_t)m * kC + d] = hh;
      ql[(size_t)m * kC + d] = ll;
    }
  }
}

// ---------------- K2: fused flash attention (32x32x16 MFMA, swizzled LDS, async dbuf) ----
// Waves: wm = row-half of the 64 S-rows, wn = col-half. Softmax state is made
// consistent across the wn-pair via a 1 KB LDS exchange (xred) each tile.
__global__ __launch_bounds__(256, 2) void k_attn(
    const __bf16* __restrict__ th, const __bf16* __restrict__ tl,
    const __bf16* __restrict__ qh, const __bf16* __restrict__ ql,
    const __bf16* __restrict__ xbt, float* __restrict__ out) {
  __shared__ __align__(16) __bf16 lds[24576];
  __shared__ float xred[2][2][64];   // [max|sum][wn][row]

  int bid = blockIdx.x;                       // 512
  int b   = (bid & 7) | ((bid >> 8) << 3);
  int s0  = ((bid >> 3) & 31) * 64;

  int tid  = threadIdx.x;
  int lane = tid & 63;
  int wave = tid >> 6;
  int wm   = wave >> 1;        // 0..1 : m-half of S / O rows
  int wn   = wave & 1;         // 0..1 : n-half
  int h    = lane >> 5;        // half-wave (k-half of fragments)
  int l31  = lane & 31;

  const float LOG2E = 1.4426950408889634f;
  const size_t rowbase = (size_t)b * kS;

  int rA  = wm * 32 + l31;     // score A row (s-local); also P row for PV A-frags
  int rB0 = wn * 64 + l31;     // score B rows, tile 0
  int rB1 = rB0 + 32;          // tile 1
  int rX  = wn * 32 + l31;     // PV B row (c-local within a 64-col chunk)

  float m_r[16], l_r[16];
#pragma unroll
  for (int g = 0; g < 16; ++g) { m_r[g] = -INFINITY; l_r[g] = 0.f; }
  f32x16 O[8] = {};

  for (int tt = 0; tt < 16; ++tt) {
    int t0 = tt * 128;
    f32x16 S0 = {}, S1 = {};

    auto stage_score = [&](int kc, int bsel) {
      __bf16* buf = lds + bsel * 12288;
      {
        int p = wave * 64 + lane;              // 256 chunk slots: A is 64x4
        int r = p >> 2;
        int c = (p & 3) ^ (r & 3);
        size_t g = (rowbase + s0 + r) * (size_t)kC + kc * 32 + c * 8;
        gl2lds16(th + g, buf + p * 8);
        gl2lds16(tl + g, buf + 2048 + p * 8);
      }
#pragma unroll
      for (int i = 0; i < 2; ++i) {            // B is 128x4 = 512 slots
        int p = (wave * 2 + i) * 64 + lane;
        int r = p >> 2;
        int c = (p & 3) ^ (r & 3);
        size_t g = (rowbase + t0 + r) * (size_t)kC + kc * 32 + c * 8;
        gl2lds16(qh + g, buf + 4096 + p * 8);
        gl2lds16(ql + g, buf + 8192 + p * 8);
      }
    };

    auto compute_score = [&](int bsel) {
      const __bf16* buf = lds + bsel * 12288;
      const __bf16* Ah = buf;
      const __bf16* Al = buf + 2048;
      const __bf16* Bh = buf + 4096;
      const __bf16* Bl = buf + 8192;
#pragma unroll
      for (int ks = 0; ks < 2; ++ks) {
        int cc = ks * 2 + h;
        int oA  = rA  * 32 + (cc ^ (rA  & 3)) * 8;
        int oB0 = rB0 * 32 + (cc ^ (rB0 & 3)) * 8;
        int oB1 = rB1 * 32 + (cc ^ (rB1 & 3)) * 8;
        bf16x8 ah  = *(const bf16x8*)&Ah[oA];
        bf16x8 al  = *(const bf16x8*)&Al[oA];
        bf16x8 bh0 = *(const bf16x8*)&Bh[oB0];
        bf16x8 bl0 = *(const bf16x8*)&Bl[oB0];
        bf16x8 bh1 = *(const bf16x8*)&Bh[oB1];
        bf16x8 bl1 = *(const bf16x8*)&Bl[oB1];
        S0 = MFMA32(ah, bh0, S0);
        S0 = MFMA32(ah, bl0, S0);
        S0 = MFMA32(al, bh0, S0);
        S1 = MFMA32(ah, bh1, S1);
        S1 = MFMA32(ah, bl1, S1);
        S1 = MFMA32(al, bh1, S1);
      }
    };

    // ----- score: S[64x128] = T . Q^T over K=512, 32-wide K chunks, dbuf -----
    stage_score(0, 0);
    __syncthreads();
    for (int kc = 0; kc < 16; ++kc) {
      if (kc < 15) stage_score(kc + 1, (kc + 1) & 1);
      compute_score(kc & 1);
      __syncthreads();
    }

    // ----- online softmax; rows per lane: rr = 4h + (g&3) + 8(g>>2) -----
    float mnew[16];
#pragma unroll
    for (int g = 0; g < 16; ++g) mnew[g] = fmaxf(S0[g], S1[g]);
#pragma unroll
    for (int mk = 1; mk <= 16; mk <<= 1)
#pragma unroll
      for (int g = 0; g < 16; ++g)
        mnew[g] = fmaxf(mnew[g], __shfl_xor(mnew[g], mk, 64));
    // cross-wave combine: each wn-half only saw 64 of the 128 columns
    if (l31 == 0) {
#pragma unroll
      for (int g = 0; g < 16; ++g) {
        int rr = 4 * h + (g & 3) + 8 * (g >> 2);
        xred[0][wn][wm * 32 + rr] = mnew[g];
      }
    }
    __syncthreads();
#pragma unroll
    for (int g = 0; g < 16; ++g) {
      int rr = 4 * h + (g & 3) + 8 * (g >> 2);
      mnew[g] = fmaxf(mnew[g], xred[0][1 - wn][wm * 32 + rr]);
    }
    float alpha[16], rsum[16];
#pragma unroll
    for (int g = 0; g < 16; ++g) {
      float mn = fmaxf(m_r[g], mnew[g]);
      alpha[g] = exp2f((m_r[g] - mn) * LOG2E);
      m_r[g] = mn;
      float p0 = exp2f((S0[g] - mn) * LOG2E);
      float p1 = exp2f((S1[g] - mn) * LOG2E);
      S0[g] = p0; S1[g] = p1;
      rsum[g] = p0 + p1;
    }
#pragma unroll
    for (int mk = 1; mk <= 16; mk <<= 1)
#pragma unroll
      for (int g = 0; g < 16; ++g)
        rsum[g] += __shfl_xor(rsum[g], mk, 64);
    if (l31 == 0) {
#pragma unroll
      for (int g = 0; g < 16; ++g) {
        int rr = 4 * h + (g & 3) + 8 * (g >> 2);
        xred[1][wn][wm * 32 + rr] = rsum[g];
      }
    }
    __syncthreads();
#pragma unroll
    for (int g = 0; g < 16; ++g) {
      int rr = 4 * h + (g & 3) + 8 * (g >> 2);
      rsum[g] += xred[1][1 - wn][wm * 32 + rr];
      l_r[g] = l_r[g] * alpha[g] + rsum[g];
    }
#pragma unroll
    for (int nc = 0; nc < 8; ++nc)
#pragma unroll
      for (int g = 0; g < 16; ++g) O[nc][g] *= alpha[g];

    // ----- P write: [64][128] swizzled @ lds[0] (C-layout -> A-layout) -----
#pragma unroll
    for (int g = 0; g < 16; ++g) {
      int rr = 4 * h + (g & 3) + 8 * (g >> 2);
      int r  = wm * 32 + rr;
      int rx = r & 7;
      int cb0 = (wn * 64 + l31) >> 3;
      int ph0 = (cb0 & 8) | ((cb0 & 7) ^ rx);
      lds[r * 128 + ph0 * 8 + (l31 & 7)] = (__bf16)S0[g];
      int cb1 = cb0 + 4;
      int ph1 = (cb1 & 8) | ((cb1 & 7) ^ rx);
      lds[r * 128 + ph1 * 8 + (l31 & 7)] = (__bf16)S1[g];
    }
    __syncthreads();

    // ----- PV: O[64x512] += P[64x128] . Xbt[128x512], P-frags persisted -----
    bf16x8 pa[8];
#pragma unroll
    for (int ks = 0; ks < 8; ++ks) {
      int cc = ks * 2 + h;
      int ph = (cc & 8) | ((cc & 7) ^ (rA & 7));
      pa[ks] = *(const bf16x8*)&lds[rA * 128 + ph * 8];
    }

    auto stage_xt = [&](int nc, int bsel) {
      __bf16* xb = lds + 8192 + bsel * 8192;
#pragma unroll
      for (int i = 0; i < 4; ++i) {
        int p = (wave * 4 + i) * 64 + lane;    // 1024 chunk slots: Xt is 64x16
        int r = p >> 4;
        int pc = p & 15;
        int c = (pc & 8) | ((pc & 7) ^ (r & 7));
        gl2lds16(xbt + ((size_t)b * kC + nc * 64 + r) * (size_t)kS + t0 + c * 8,
                 xb + p * 8);
      }
    };

    stage_xt(0, 0);
    __syncthreads();
    for (int nc = 0; nc < 8; ++nc) {
      if (nc < 7) stage_xt(nc + 1, (nc + 1) & 1);
      const __bf16* xb = lds + 8192 + (nc & 1) * 8192;
      f32x16 o = O[nc];
#pragma unroll
      for (int ks = 0; ks < 8; ++ks) {
        int cc = ks * 2 + h;
        int ph = (cc & 8) | ((cc & 7) ^ (rX & 7));
        bf16x8 x8 = *(const bf16x8*)&xb[rX * 128 + ph * 8];
        o = MFMA32(pa[ks], x8, o);
      }
      O[nc] = o;
      __syncthreads();
    }
  }

  // ----- epilogue: out = tanh(O / l) -----
#pragma unroll
  for (int g = 0; g < 16; ++g) {
    int rr = 4 * h + (g & 3) + 8 * (g >> 2);
    float inv = __builtin_amdgcn_rcpf(l_r[g]);
    size_t ro = (rowbase + s0 + wm * 32 + rr) * (size_t)kC + wn * 32 + l31;
#pragma unroll
    for (int nc = 0; nc < 8; ++nc) {
      float v = O[nc][g] * inv;
      float e = exp2f(2.f * LOG2E * v);
      out[ro + nc * 64] = 1.f - 2.f * __builtin_amdgcn_rcpf(e + 1.f);
    }
  }
}

extern "C" void kernel_launch(void* const* d_in, const int* in_sizes, int n_in,
                              void* d_out, int out_size, void* d_ws, size_t ws_size,
                              hipStream_t stream) {
  const float* x    = (const float*)d_in[0];
  const float* xp   = (const float*)d_in[1];
  const float* W    = (const float*)d_in[2];
  const float* bias = (const float*)d_in[3];
  float* out = (float*)d_out;

  __bf16* ws  = (__bf16*)d_ws;
  __bf16* th  = ws;
  __bf16* tl  = ws + kNE;
  __bf16* qh  = ws + 2 * kNE;
  __bf16* ql  = ws + 3 * kNE;
  __bf16* xbt = ws + 4 * kNE;

  k_tanh_split<<<8192, 256, 0, stream>>>(xp, th, tl);
  k_transpose_x<<<4096, 256, 0, stream>>>(x, xbt);
  k_qgemm<<<4096, 256, 0, stream>>>(xp, W, bias, qh, ql);
  k_attn<<<512, 256, 0, stream>>>(th, tl, qh, ql, xbt, out);
}